// Round 4
// baseline (589.931 us; speedup 1.0000x reference)
//
#include <hip/hip_runtime.h>

// VectorQuantizer: inputs [65536,128] f32, codebook [1024,128] f32.
// Outputs flat f32: loss(1) | quantized_st(65536*128) | perplexity(1) | encodings(65536*1024)
#define NROWS 65536
#define DIM   128
#define KC    1024
#define QST_OFF  1
#define PPL_OFF  8388609
#define ENC_OFF  8388610

typedef float f32x2 __attribute__((ext_vector_type(2)));
typedef float floatx4 __attribute__((ext_vector_type(4)));
typedef _Float16 half8_t __attribute__((ext_vector_type(8)));
typedef _Float16 half4_t __attribute__((ext_vector_type(4)));

// B-tile LDS/global stride: 144 halfs (288 B) -> balanced banks for MFMA frag reads
#define BSTR 144
#define TILEH (64 * BSTR)          // 9216 halfs per split tile
#define CHUNKH (2 * TILEH)         // 18432 halfs per chunk (hi+lo)

// --- rounding-exact helpers: replicate numpy's elementwise fp32 ops, no FMA contraction ---
__device__ __forceinline__ float fadd_rn_(float a, float b) {
#pragma clang fp contract(off)
  return a + b;
}
__device__ __forceinline__ float fsub_rn_(float a, float b) {
#pragma clang fp contract(off)
  return a - b;
}
__device__ __forceinline__ float fmul_rn_(float a, float b) {
#pragma clang fp contract(off)
  return a * b;
}

// K1: row sum-of-squares with numpy pairwise_sum order (n=128: 8 accumulators).
__global__ __launch_bounds__(256) void k_rowsq(const float* __restrict__ inp,
                                               const float* __restrict__ cb,
                                               float* __restrict__ xx,
                                               float* __restrict__ cc) {
  int tid = blockIdx.x * 256 + threadIdx.x;
  const float* src;
  float* dst;
  if (tid < NROWS) {
    src = inp + (size_t)tid * DIM;
    dst = xx + tid;
  } else if (tid < NROWS + KC) {
    src = cb + (size_t)(tid - NROWS) * DIM;
    dst = cc + (tid - NROWS);
  } else {
    return;
  }
  float r[8];
  {
    float4 v0 = *(const float4*)(src);
    float4 v1 = *(const float4*)(src + 4);
    r[0] = fmul_rn_(v0.x, v0.x); r[1] = fmul_rn_(v0.y, v0.y);
    r[2] = fmul_rn_(v0.z, v0.z); r[3] = fmul_rn_(v0.w, v0.w);
    r[4] = fmul_rn_(v1.x, v1.x); r[5] = fmul_rn_(v1.y, v1.y);
    r[6] = fmul_rn_(v1.z, v1.z); r[7] = fmul_rn_(v1.w, v1.w);
  }
  for (int t = 1; t < 16; ++t) {
    float4 v0 = *(const float4*)(src + t * 8);
    float4 v1 = *(const float4*)(src + t * 8 + 4);
    r[0] = fadd_rn_(r[0], fmul_rn_(v0.x, v0.x));
    r[1] = fadd_rn_(r[1], fmul_rn_(v0.y, v0.y));
    r[2] = fadd_rn_(r[2], fmul_rn_(v0.z, v0.z));
    r[3] = fadd_rn_(r[3], fmul_rn_(v0.w, v0.w));
    r[4] = fadd_rn_(r[4], fmul_rn_(v1.x, v1.x));
    r[5] = fadd_rn_(r[5], fmul_rn_(v1.y, v1.y));
    r[6] = fadd_rn_(r[6], fmul_rn_(v1.z, v1.z));
    r[7] = fadd_rn_(r[7], fmul_rn_(v1.w, v1.w));
  }
  float res = fadd_rn_(fadd_rn_(fadd_rn_(r[0], r[1]), fadd_rn_(r[2], r[3])),
                       fadd_rn_(fadd_rn_(r[4], r[5]), fadd_rn_(r[6], r[7])));
  *dst = res;
}

// K1b: transpose codebook -> cbT [128][1024] f32 (for k_fix coalesced reads).
__global__ __launch_bounds__(256) void k_tr(const float* __restrict__ cb,
                                            float* __restrict__ cbT) {
  __shared__ float tile[64 * 129];
  int t = threadIdx.x;
  int c0 = blockIdx.x * 64;
#pragma unroll
  for (int it = 0; it < 32; ++it) {
    int f = it * 256 + t;
    int c = f >> 7, d = f & 127;
    tile[c * 129 + d] = cb[(size_t)(c0 + c) * DIM + d];
  }
  __syncthreads();
#pragma unroll
  for (int it = 0; it < 32; ++it) {
    int f = it * 256 + t;
    int d = f >> 6, c = f & 63;
    cbT[(size_t)d * KC + c0 + c] = tile[c * 129 + d];
  }
}

// K1c: codebook -> fp16 hi/lo split, pre-scaled by 512 (exact pow2), packed per
// 64-code chunk with LDS-image layout [chunk][hi 64x144 | lo 64x144].
__global__ __launch_bounds__(256) void k_prep_b(const float* __restrict__ cb,
                                                _Float16* __restrict__ Bp) {
  int tid = blockIdx.x * 256 + threadIdx.x;
  if (tid >= KC * DIM) return;
  int code = tid >> 7, k = tid & 127;
  float c5 = cb[tid] * 512.0f;            // exact
  _Float16 h = (_Float16)c5;
  _Float16 l = (_Float16)(c5 - (float)h); // Sterbenz-exact residual, then f16 round
  int chunk = code >> 6, cr = code & 63;
  size_t base = (size_t)chunk * CHUNKH;
  Bp[base + cr * BSTR + k] = h;
  Bp[base + TILEH + cr * BSTR + k] = l;
}

// K2: MFMA distance GEMM + margin-checked argmin.
// Block: 64 rows, 256 thr = 4 waves (wave = one 16-row MFMA rowtile).
// A: fp16 hi/lo split staged in LDS once, frags then held in regs (LDS reused for B).
// B: 16 chunks of 64 codes, register-prefetched global->LDS single buffer.
// m = 512*x.c computed as xh*ch + xh*cl + xl*ch via mfma_f32_16x16x32_f16;
// dist = fl(fl(xx+cc) - m*2^-8) (exact pow2 unscale = fl(2*matmul)).
// Rows whose top-2 gap < 3 ulp are flagged for exact fp32 recheck in k_fix.
__global__ __launch_bounds__(256) void k_main(const float* __restrict__ inp,
                                              const _Float16* __restrict__ Bp,
                                              const float* __restrict__ xx,
                                              const float* __restrict__ cc,
                                              int* __restrict__ idxrow,
                                              int* __restrict__ nflag,
                                              int* __restrict__ flist) {
  __shared__ _Float16 SB[CHUNKH];  // 36864 B; A-split first, then B chunks
  int t = threadIdx.x;
  int lane = t & 63, w = t >> 6;
  int q = lane >> 4, col = lane & 15;
  int row0 = blockIdx.x * 64;

  // ---- stage A as fp16 hi/lo split into SB ----
  {
    int r = t & 63, seg = t >> 6;
    const float* src = inp + (size_t)(row0 + r) * DIM + seg * 32;
#pragma unroll
    for (int i = 0; i < 8; ++i) {
      float4 v = *(const float4*)(src + i * 4);
      _Float16 h0 = (_Float16)v.x, h1 = (_Float16)v.y, h2 = (_Float16)v.z, h3 = (_Float16)v.w;
      half4_t hv = {h0, h1, h2, h3};
      half4_t lv = {(_Float16)(v.x - (float)h0), (_Float16)(v.y - (float)h1),
                    (_Float16)(v.z - (float)h2), (_Float16)(v.w - (float)h3)};
      int k = seg * 32 + i * 4;
      *(half4_t*)&SB[r * BSTR + k] = hv;
      *(half4_t*)&SB[TILEH + r * BSTR + k] = lv;
    }
  }
  __syncthreads();

  // ---- A frags -> registers (held for whole kernel) ----
  int arow = w * 16 + col;
  half8_t ah[4], al[4];
#pragma unroll
  for (int ks = 0; ks < 4; ++ks) {
    ah[ks] = *(const half8_t*)&SB[arow * BSTR + ks * 32 + q * 8];
    al[ks] = *(const half8_t*)&SB[TILEH + arow * BSTR + ks * 32 + q * 8];
  }

  float xr[4];
#pragma unroll
  for (int r = 0; r < 4; ++r) xr[r] = xx[row0 + w * 16 + q * 4 + r];

  float b1[4], b2[4];
  int i1[4];
#pragma unroll
  for (int r = 0; r < 4; ++r) { b1[r] = 3.4e38f; b2[r] = 3.4e38f; i1[r] = 0; }

  // ---- B chunk pipeline: regs hold next chunk while MFMA consumes current ----
  const float4* bp4 = (const float4*)Bp;  // chunk stride = CHUNKH*2/16 = 2304 float4
  float4 breg[9];
#pragma unroll
  for (int r = 0; r < 9; ++r) breg[r] = bp4[r * 256 + t];

  for (int c = 0; c < 16; ++c) {
    __syncthreads();  // prior chunk's LDS reads complete (and A-frag reads, iter 0)
#pragma unroll
    for (int r = 0; r < 9; ++r) *(float4*)&SB[(r * 256 + t) * 8] = breg[r];
    __syncthreads();
    if (c < 15) {
#pragma unroll
      for (int r = 0; r < 9; ++r) breg[r] = bp4[(c + 1) * 2304 + r * 256 + t];
    }

    float cck[4];
#pragma unroll
    for (int ct = 0; ct < 4; ++ct) cck[ct] = cc[c * 64 + ct * 16 + col];

    floatx4 acc[4];
#pragma unroll
    for (int ct = 0; ct < 4; ++ct) acc[ct] = (floatx4){0.f, 0.f, 0.f, 0.f};

#pragma unroll
    for (int ks = 0; ks < 4; ++ks) {
#pragma unroll
      for (int ct = 0; ct < 4; ++ct) {
        int brow = ct * 16 + col;
        half8_t bh = *(const half8_t*)&SB[brow * BSTR + ks * 32 + q * 8];
        half8_t bl = *(const half8_t*)&SB[TILEH + brow * BSTR + ks * 32 + q * 8];
        acc[ct] = __builtin_amdgcn_mfma_f32_16x16x32_f16(ah[ks], bh, acc[ct], 0, 0, 0);
        acc[ct] = __builtin_amdgcn_mfma_f32_16x16x32_f16(ah[ks], bl, acc[ct], 0, 0, 0);
        acc[ct] = __builtin_amdgcn_mfma_f32_16x16x32_f16(al[ks], bh, acc[ct], 0, 0, 0);
      }
    }

#pragma unroll
    for (int ct = 0; ct < 4; ++ct) {
#pragma unroll
      for (int r = 0; r < 4; ++r) {
        float m2 = fmul_rn_(acc[ct][r], 0.00390625f);  // = fl(2*matmul), exact scale
        float dist = fsub_rn_(fadd_rn_(xr[r], cck[ct]), m2);
        int kidx = c * 64 + ct * 16 + col;
        bool lt = dist < b1[r];
        b2[r] = lt ? b1[r] : fminf(b2[r], dist);
        i1[r] = lt ? kidx : i1[r];
        b1[r] = lt ? dist : b1[r];
      }
    }
  }

  // ---- cross-lane (16 lanes of quad) top-2 reduce, tie -> lower index ----
#pragma unroll
  for (int r = 0; r < 4; ++r) {
    float v1 = b1[r], v2 = b2[r];
    int ii = i1[r];
    for (int off = 1; off < 16; off <<= 1) {
      float ov1 = __shfl_xor(v1, off);
      float ov2 = __shfl_xor(v2, off);
      int oi = __shfl_xor(ii, off);
      float nb1 = fminf(v1, ov1);
      float nb2 = fminf(fmaxf(v1, ov1), fminf(v2, ov2));
      ii = (ov1 < v1) ? oi : ((ov1 > v1) ? ii : min(ii, oi));
      v1 = nb1; v2 = nb2;
    }
    b1[r] = v1; b2[r] = v2; i1[r] = ii;
  }

  if (col == 0) {
#pragma unroll
    for (int r = 0; r < 4; ++r) {
      int grow = row0 + w * 16 + q * 4 + r;
      idxrow[grow] = i1[r];
      // 3-ulp safety margin (split err ~1e-7 << ulp(128)/2=7.6e-6)
      float u = (b1[r] >= 256.f) ? 9.4e-5f : 4.7e-5f;
      if (b2[r] - b1[r] < u) {
        int p = atomicAdd(nflag, 1);
        flist[p] = grow;
      }
    }
  }
}

// K2b: exact fp32 recheck of flagged rows (replicates the empirically-numpy-matching
// fp32 FMA-chain path from R1). Wave = one row; 4 rows per block iteration.
__global__ __launch_bounds__(256) void k_fix(const float* __restrict__ inp,
                                             const float* __restrict__ cbT,
                                             const float* __restrict__ xx,
                                             const float* __restrict__ cc,
                                             const int* __restrict__ nflag,
                                             const int* __restrict__ flist,
                                             int* __restrict__ idxrow) {
  __shared__ float xs[4][128];
  int t = threadIdx.x, g = t >> 6, l = t & 63;
  int n = *nflag;
  for (int base = blockIdx.x * 4; base < n; base += 1024) {
    int e = base + g;
    int grow = (e < n) ? flist[e] : -1;
    if (grow >= 0) {
      float2 v = *(const float2*)&inp[(size_t)grow * DIM + l * 2];
      xs[g][l * 2] = v.x;
      xs[g][l * 2 + 1] = v.y;
    }
    __syncthreads();
    if (grow >= 0) {
      float xxr = xx[grow];
      float bb = 3.4e38f;
      int bi = 0;
#pragma unroll
      for (int cs = 0; cs < 4; ++cs) {
        int c0 = cs * 256 + l * 4;
        float a0 = 0.f, a1 = 0.f, a2 = 0.f, a3 = 0.f;
        for (int d = 0; d < 128; ++d) {
          float xd = xs[g][d];
          float4 cv = *(const float4*)&cbT[(size_t)d * KC + c0];
          a0 = __builtin_fmaf(xd, cv.x, a0);
          a1 = __builtin_fmaf(xd, cv.y, a1);
          a2 = __builtin_fmaf(xd, cv.z, a2);
          a3 = __builtin_fmaf(xd, cv.w, a3);
        }
        float aa[4] = {a0, a1, a2, a3};
#pragma unroll
        for (int j = 0; j < 4; ++j) {
          float dist = fsub_rn_(fadd_rn_(xxr, cc[c0 + j]), fmul_rn_(2.0f, aa[j]));
          if (dist < bb) { bb = dist; bi = c0 + j; }
        }
      }
      for (int off = 1; off < 64; off <<= 1) {
        float ov = __shfl_xor(bb, off);
        int oi = __shfl_xor(bi, off);
        if (ov < bb || (ov == bb && oi < bi)) { bb = ov; bi = oi; }
      }
      if (l == 0) idxrow[grow] = bi;
    }
    __syncthreads();
  }
}

// K3: epilogue — qst, one-hot encodings, histogram, loss partials (HBM-bound).
__global__ __launch_bounds__(256) void k_epi(const float* __restrict__ inp,
                                             const float* __restrict__ cb,
                                             const int* __restrict__ idxrow,
                                             float* __restrict__ out_qst,
                                             float* __restrict__ out_enc,
                                             int* __restrict__ cnt,
                                             float* __restrict__ lsum) {
  __shared__ int bk[64];
  __shared__ float red[4];
  int t = threadIdx.x;
  int row0 = blockIdx.x * 64;
  if (t < 64) {
    int k = idxrow[row0 + t];
    bk[t] = k;
    atomicAdd(&cnt[k], 1);
  }
  __syncthreads();

  float ls = 0.f;
#pragma unroll 4
  for (int it = 0; it < 32; ++it) {
    int f = it * 256 + t;
    int row = f >> 7, d = f & 127;
    size_t gro = (size_t)(row0 + row) * DIM + d;
    float x = inp[gro];
    float qv = cb[(size_t)bk[row] * DIM + d];
    float qe = fsub_rn_(qv, x);
    out_qst[gro] = fadd_rn_(x, qe);
    ls = __builtin_fmaf(qe, qe, ls);
  }

  for (int it = 0; it < 128; ++it) {
    int f2 = it * 256 + t;
    int row = f2 >> 9, c2 = f2 & 511;
    int kk = bk[row];
    f32x2 v;
    v.x = (kk == 2 * c2) ? 1.0f : 0.0f;
    v.y = (kk == 2 * c2 + 1) ? 1.0f : 0.0f;
    *(f32x2*)&out_enc[(size_t)(row0 + row) * KC + 2 * c2] = v;
  }

  for (int off = 32; off; off >>= 1) ls += __shfl_down(ls, off);
  if ((t & 63) == 0) red[t >> 6] = ls;
  __syncthreads();
  if (t == 0) atomicAdd(lsum, red[0] + red[1] + red[2] + red[3]);
}

// K4: loss + perplexity scalars
__global__ __launch_bounds__(1024) void k_scalars(const int* __restrict__ cnt,
                                                  const float* __restrict__ lsum,
                                                  float* __restrict__ out) {
  int t = threadIdx.x;
  float p = (float)cnt[t] * (1.0f / 65536.0f);
  float term = fmul_rn_(p, logf(fadd_rn_(p, 1e-10f)));
  for (int off = 32; off; off >>= 1) term += __shfl_down(term, off);
  __shared__ float red[16];
  if ((t & 63) == 0) red[t >> 6] = term;
  __syncthreads();
  if (t == 0) {
    float s = 0.f;
#pragma unroll
    for (int w = 0; w < 16; ++w) s += red[w];
    out[PPL_OFF] = expf(-s);
    float e = *lsum * (1.0f / 8388608.0f);
    out[0] = fadd_rn_(e, fmul_rn_(0.25f, e));
  }
}

extern "C" void kernel_launch(void* const* d_in, const int* in_sizes, int n_in,
                              void* d_out, int out_size, void* d_ws, size_t ws_size,
                              hipStream_t stream) {
  const float* inp = (const float*)d_in[0];
  const float* cb = (const float*)d_in[1];
  float* out = (float*)d_out;

  _Float16* Bp = (_Float16*)d_ws;          // 16*18432 halfs = 589824 B
  float* cbT = (float*)(Bp + 16 * CHUNKH); // 131072 f32 = 512 KB
  float* xx = cbT + DIM * KC;              // 65536 f32
  float* cc = xx + NROWS;                  // 1024 f32
  int* cnt = (int*)(cc + KC);              // 1024 i32
  float* lsum = (float*)(cnt + KC);        // 1
  int* nflag = (int*)(lsum + 1);           // 1
  int* idxrow = nflag + 1;                 // 65536 i32
  int* flist = idxrow + NROWS;             // 65536 i32

  (void)hipMemsetAsync(cnt, 0, (KC + 2) * sizeof(int), stream);  // cnt, lsum, nflag
  k_rowsq<<<(NROWS + KC) / 256, 256, 0, stream>>>(inp, cb, xx, cc);
  k_tr<<<KC / 64, 256, 0, stream>>>(cb, cbT);
  k_prep_b<<<(KC * DIM) / 256, 256, 0, stream>>>(cb, Bp);
  k_main<<<NROWS / 64, 256, 0, stream>>>(inp, Bp, xx, cc, idxrow, nflag, flist);
  k_fix<<<256, 256, 0, stream>>>(inp, cbT, xx, cc, nflag, flist, idxrow);
  k_epi<<<NROWS / 64, 256, 0, stream>>>(inp, cb, idxrow, out + QST_OFF, out + ENC_OFF,
                                        cnt, lsum);
  k_scalars<<<1, 1024, 0, stream>>>(cnt, lsum, out);
}

// Round 5
// 548.387 us; speedup vs baseline: 1.0758x; 1.0758x over previous
//
#include <hip/hip_runtime.h>

// VectorQuantizer: inputs [65536,128] f32, codebook [1024,128] f32.
// Outputs flat f32: loss(1) | quantized_st(65536*128) | perplexity(1) | encodings(65536*1024)
#define NROWS 65536
#define DIM   128
#define KC    1024
#define QST_OFF  1
#define PPL_OFF  8388609
#define ENC_OFF  8388610

typedef float f32x2 __attribute__((ext_vector_type(2)));
typedef float floatx4 __attribute__((ext_vector_type(4)));
typedef _Float16 half8_t __attribute__((ext_vector_type(8)));
typedef _Float16 half4_t __attribute__((ext_vector_type(4)));

// B/A LDS stride: 144 halfs (288 B)
#define BSTR 144
#define TILEH (64 * BSTR)          // 9216 halfs per split tile
#define CHUNKH (2 * TILEH)         // 18432 halfs per chunk (hi+lo)

// --- rounding-exact helpers: numpy-replica fp32 elementwise ops, no contraction ---
__device__ __forceinline__ float fadd_rn_(float a, float b) {
#pragma clang fp contract(off)
  return a + b;
}
__device__ __forceinline__ float fsub_rn_(float a, float b) {
#pragma clang fp contract(off)
  return a - b;
}
__device__ __forceinline__ float fmul_rn_(float a, float b) {
#pragma clang fp contract(off)
  return a * b;
}

// numpy pairwise_sum(x*x) for n=128: 8 accumulators, strided, fixed combine tree.
// (op-order identical to the R1-validated k_rowsq)
__device__ __forceinline__ float rowsq128(const float4* src) {
  float r[8];
  {
    float4 v0 = src[0], v1 = src[1];
    r[0] = fmul_rn_(v0.x, v0.x); r[1] = fmul_rn_(v0.y, v0.y);
    r[2] = fmul_rn_(v0.z, v0.z); r[3] = fmul_rn_(v0.w, v0.w);
    r[4] = fmul_rn_(v1.x, v1.x); r[5] = fmul_rn_(v1.y, v1.y);
    r[6] = fmul_rn_(v1.z, v1.z); r[7] = fmul_rn_(v1.w, v1.w);
  }
  for (int i = 1; i < 16; ++i) {
    float4 v0 = src[2 * i], v1 = src[2 * i + 1];
    r[0] = fadd_rn_(r[0], fmul_rn_(v0.x, v0.x));
    r[1] = fadd_rn_(r[1], fmul_rn_(v0.y, v0.y));
    r[2] = fadd_rn_(r[2], fmul_rn_(v0.z, v0.z));
    r[3] = fadd_rn_(r[3], fmul_rn_(v0.w, v0.w));
    r[4] = fadd_rn_(r[4], fmul_rn_(v1.x, v1.x));
    r[5] = fadd_rn_(r[5], fmul_rn_(v1.y, v1.y));
    r[6] = fadd_rn_(r[6], fmul_rn_(v1.z, v1.z));
    r[7] = fadd_rn_(r[7], fmul_rn_(v1.w, v1.w));
  }
  return fadd_rn_(fadd_rn_(fadd_rn_(r[0], r[1]), fadd_rn_(r[2], r[3])),
                  fadd_rn_(fadd_rn_(r[4], r[5]), fadd_rn_(r[6], r[7])));
}

// K_prep (16 blocks x 64 codes): codebook -> cbT [128][1024] f32 (transpose),
// cc[k] exact rowsq chain, and fp16 hi/lo split pack Bp (pre-scaled x512).
__global__ __launch_bounds__(256) void k_prep(const float* __restrict__ cb,
                                              float* __restrict__ cbT,
                                              float* __restrict__ cc,
                                              _Float16* __restrict__ Bp) {
  __shared__ float tile[64 * 129];  // +1 pad: conflict-free transpose
  int t = threadIdx.x;
  int c0 = blockIdx.x * 64;
#pragma unroll
  for (int it = 0; it < 32; ++it) {
    int f = it * 256 + t;
    int c = f >> 7, d = f & 127;
    tile[c * 129 + d] = cb[(size_t)(c0 + c) * DIM + d];
  }
  __syncthreads();
#pragma unroll
  for (int it = 0; it < 32; ++it) {
    int f = it * 256 + t;
    int d = f >> 6, c = f & 63;
    cbT[(size_t)d * KC + c0 + c] = tile[c * 129 + d];
  }
  if (t < 64) {
    // exact cc chain (scalar reads from LDS, same op order as rowsq128)
    const float* s = &tile[t * 129];
    float r[8];
#pragma unroll
    for (int j = 0; j < 8; ++j) r[j] = fmul_rn_(s[j], s[j]);
    for (int i = 1; i < 16; ++i) {
#pragma unroll
      for (int j = 0; j < 8; ++j)
        r[j] = fadd_rn_(r[j], fmul_rn_(s[i * 8 + j], s[i * 8 + j]));
    }
    cc[c0 + t] = fadd_rn_(fadd_rn_(fadd_rn_(r[0], r[1]), fadd_rn_(r[2], r[3])),
                          fadd_rn_(fadd_rn_(r[4], r[5]), fadd_rn_(r[6], r[7])));
  }
  // fp16 split pack: chunk = blockIdx.x, layout [hi 64x144 | lo 64x144]
  size_t base = (size_t)blockIdx.x * CHUNKH;
#pragma unroll
  for (int it = 0; it < 32; ++it) {
    int f = it * 256 + t;
    int c = f >> 7, k = f & 127;
    float c5 = tile[c * 129 + k] * 512.0f;  // exact pow2 scale
    _Float16 h = (_Float16)c5;
    _Float16 l = (_Float16)(c5 - (float)h);
    Bp[base + c * BSTR + k] = h;
    Bp[base + TILEH + c * BSTR + k] = l;
  }
}

// K_main: per block 64 rows -> everything.
//  A: fp16 hi/lo split staged in LDS, frags -> regs; exact xx chain (L1-hot re-read).
//  GEMM: 16 chunks of 64 codes, reg-prefetch global->LDS; m = xh*ch+xh*cl+xl*ch
//  via mfma_f32_16x16x32_f16; dist = fl(fl(xx+cc) - fl(2*matmul)); top-2 margin.
//  Rows with approx gap < 3 ulp: inline exact fp32 recheck (numpy-replica).
//  Epilogue: histogram, qst+loss, one-hot encodings (16B interior stores).
__global__ __launch_bounds__(256, 4) void k_main(const float* __restrict__ inp,
                                                 const float* __restrict__ cb,
                                                 const float* __restrict__ cbT,
                                                 const _Float16* __restrict__ Bp,
                                                 const float* __restrict__ cc,
                                                 float* __restrict__ out_qst,
                                                 float* __restrict__ out_enc,
                                                 int* __restrict__ cnt,
                                                 float* __restrict__ lsum) {
  __shared__ _Float16 SB[CHUNKH];  // 36864 B: A-split image, then B chunk images
  __shared__ float xxs[64];
  __shared__ int bk[64];
  __shared__ int fl_rows[64];
  __shared__ int fl_cnt;
  __shared__ float xs[128];
  __shared__ float redd[4];
  __shared__ int redi[4];
  __shared__ float redf[4];

  int t = threadIdx.x;
  int lane = t & 63, w = t >> 6;
  int q = lane >> 4, col = lane & 15;
  int row0 = blockIdx.x * 64;
  if (t == 0) fl_cnt = 0;

  // B chunk-0 prefetch into regs (all threads) — in flight during A staging
  const float4* bp4 = (const float4*)Bp;  // chunk stride = 2304 float4
  float4 breg[9];
#pragma unroll
  for (int r = 0; r < 9; ++r) breg[r] = bp4[r * 256 + t];

  // ---- stage A as fp16 hi/lo split (all threads, coalesced) ----
  {
    int r = t & 63, seg = t >> 6;
    const float* src = inp + (size_t)(row0 + r) * DIM + seg * 32;
#pragma unroll
    for (int i = 0; i < 8; ++i) {
      float4 v = *(const float4*)(src + i * 4);
      _Float16 h0 = (_Float16)v.x, h1 = (_Float16)v.y, h2 = (_Float16)v.z, h3 = (_Float16)v.w;
      half4_t hv = {h0, h1, h2, h3};
      half4_t lv = {(_Float16)(v.x - (float)h0), (_Float16)(v.y - (float)h1),
                    (_Float16)(v.z - (float)h2), (_Float16)(v.w - (float)h3)};
      int k = seg * 32 + i * 4;
      *(half4_t*)&SB[r * BSTR + k] = hv;
      *(half4_t*)&SB[TILEH + r * BSTR + k] = lv;
    }
  }
  // exact xx chain, one lane per row (rows just fetched -> L1/L2-hot)
  if (t < 64) xxs[t] = rowsq128((const float4*)(inp + (size_t)(row0 + t) * DIM));
  __syncthreads();

  // ---- A frags -> registers ----
  int arow = w * 16 + col;
  half8_t ah[4], al[4];
#pragma unroll
  for (int ks = 0; ks < 4; ++ks) {
    ah[ks] = *(const half8_t*)&SB[arow * BSTR + ks * 32 + q * 8];
    al[ks] = *(const half8_t*)&SB[TILEH + arow * BSTR + ks * 32 + q * 8];
  }
  float xr[4];
#pragma unroll
  for (int r = 0; r < 4; ++r) xr[r] = xxs[w * 16 + q * 4 + r];

  float b1[4], b2[4];
  int i1[4];
#pragma unroll
  for (int r = 0; r < 4; ++r) { b1[r] = 3.4e38f; b2[r] = 3.4e38f; i1[r] = 0; }

  for (int c = 0; c < 16; ++c) {
    __syncthreads();  // prior chunk LDS reads (and A-frag reads, iter 0) complete
#pragma unroll
    for (int r = 0; r < 9; ++r) *(float4*)&SB[(r * 256 + t) * 8] = breg[r];
    __syncthreads();
    if (c < 15) {
#pragma unroll
      for (int r = 0; r < 9; ++r) breg[r] = bp4[(c + 1) * 2304 + r * 256 + t];
    }

    float cck[4];
#pragma unroll
    for (int ct = 0; ct < 4; ++ct) cck[ct] = cc[c * 64 + ct * 16 + col];

    floatx4 acc[4];
#pragma unroll
    for (int ct = 0; ct < 4; ++ct) acc[ct] = (floatx4){0.f, 0.f, 0.f, 0.f};

#pragma unroll
    for (int ks = 0; ks < 4; ++ks) {
#pragma unroll
      for (int ct = 0; ct < 4; ++ct) {
        int brow = ct * 16 + col;
        half8_t bh = *(const half8_t*)&SB[brow * BSTR + ks * 32 + q * 8];
        half8_t bl = *(const half8_t*)&SB[TILEH + brow * BSTR + ks * 32 + q * 8];
        acc[ct] = __builtin_amdgcn_mfma_f32_16x16x32_f16(ah[ks], bh, acc[ct], 0, 0, 0);
        acc[ct] = __builtin_amdgcn_mfma_f32_16x16x32_f16(ah[ks], bl, acc[ct], 0, 0, 0);
        acc[ct] = __builtin_amdgcn_mfma_f32_16x16x32_f16(al[ks], bh, acc[ct], 0, 0, 0);
      }
    }

#pragma unroll
    for (int ct = 0; ct < 4; ++ct) {
#pragma unroll
      for (int r = 0; r < 4; ++r) {
        float m2 = fmul_rn_(acc[ct][r], 0.00390625f);  // fl(2*matmul), exact unscale
        float dist = fsub_rn_(fadd_rn_(xr[r], cck[ct]), m2);
        int kidx = c * 64 + ct * 16 + col;
        bool lt = dist < b1[r];
        b2[r] = lt ? b1[r] : fminf(b2[r], dist);
        i1[r] = lt ? kidx : i1[r];
        b1[r] = lt ? dist : b1[r];
      }
    }
  }

  // top-2 reduce across the 16 col-lanes; tie -> lower index
#pragma unroll
  for (int r = 0; r < 4; ++r) {
    float v1 = b1[r], v2 = b2[r];
    int ii = i1[r];
    for (int off = 1; off < 16; off <<= 1) {
      float ov1 = __shfl_xor(v1, off);
      float ov2 = __shfl_xor(v2, off);
      int oi = __shfl_xor(ii, off);
      float nb1 = fminf(v1, ov1);
      float nb2 = fminf(fmaxf(v1, ov1), fminf(v2, ov2));
      ii = (ov1 < v1) ? oi : ((ov1 > v1) ? ii : min(ii, oi));
      v1 = nb1; v2 = nb2;
    }
    b1[r] = v1; b2[r] = v2; i1[r] = ii;
  }

  if (col == 0) {
#pragma unroll
    for (int r = 0; r < 4; ++r) {
      int lrow = w * 16 + q * 4 + r;
      bk[lrow] = i1[r];
      float u = (b1[r] >= 256.f) ? 9.4e-5f : 4.7e-5f;  // 3-ulp tiered margin
      if (b2[r] - b1[r] < u) {
        int p = atomicAdd(&fl_cnt, 1);
        fl_rows[p] = lrow;
      }
    }
  }
  __syncthreads();

  // ---- inline exact fp32 recheck of flagged rows ----
  int nf = fl_cnt;
  for (int f = 0; f < nf; ++f) {
    int row = fl_rows[f];
    if (t < 128) xs[t] = inp[(size_t)(row0 + row) * DIM + t];
    __syncthreads();
    float xxr = xxs[row];
    int c0 = t * 4;
    float a0 = 0.f, a1 = 0.f, a2 = 0.f, a3 = 0.f;
    for (int d = 0; d < 128; ++d) {
      float xd = xs[d];
      float4 cv = *(const float4*)&cbT[(size_t)d * KC + c0];
      a0 = __builtin_fmaf(xd, cv.x, a0);
      a1 = __builtin_fmaf(xd, cv.y, a1);
      a2 = __builtin_fmaf(xd, cv.z, a2);
      a3 = __builtin_fmaf(xd, cv.w, a3);
    }
    float aa[4] = {a0, a1, a2, a3};
    float bb = 3.4e38f;
    int bi = 0;
#pragma unroll
    for (int j = 0; j < 4; ++j) {
      float dist = fsub_rn_(fadd_rn_(xxr, cc[c0 + j]), fmul_rn_(2.0f, aa[j]));
      if (dist < bb) { bb = dist; bi = c0 + j; }
    }
    for (int off = 1; off < 64; off <<= 1) {
      float ov = __shfl_xor(bb, off);
      int oi = __shfl_xor(bi, off);
      if (ov < bb || (ov == bb && oi < bi)) { bb = ov; bi = oi; }
    }
    if (lane == 0) { redd[w] = bb; redi[w] = bi; }
    __syncthreads();
    if (t == 0) {
      float vb = redd[0];
      int ib = redi[0];
#pragma unroll
      for (int ww = 1; ww < 4; ++ww) {
        if (redd[ww] < vb || (redd[ww] == vb && redi[ww] < ib)) { vb = redd[ww]; ib = redi[ww]; }
      }
      bk[row] = ib;
    }
    __syncthreads();
  }

  // ---- epilogue ----
  if (t < 64) atomicAdd(&cnt[bk[t]], 1);

  float ls = 0.f;
#pragma unroll 4
  for (int it = 0; it < 32; ++it) {
    int f = it * 256 + t;
    int row = f >> 7, d = f & 127;
    size_t gro = (size_t)(row0 + row) * DIM + d;
    float x = inp[gro];
    float qv = cb[(size_t)bk[row] * DIM + d];
    float qe = fsub_rn_(qv, x);
    out_qst[gro] = fadd_rn_(x, qe);  // == np: inputs + (quantized - inputs)
    ls = __builtin_fmaf(qe, qe, ls);
  }

  // encodings: per row, 255 interior float4 (16B-aligned at enc+2) + head/tail 8B
  for (int row = 0; row < 64; ++row) {
    int kk = bk[row];
    size_t rb = (size_t)(row0 + row) * KC;
    if (t < 255) {
      int cI = 2 + 4 * t;
      float4 v;
      v.x = (kk == cI) ? 1.0f : 0.0f;
      v.y = (kk == cI + 1) ? 1.0f : 0.0f;
      v.z = (kk == cI + 2) ? 1.0f : 0.0f;
      v.w = (kk == cI + 3) ? 1.0f : 0.0f;
      *(float4*)&out_enc[rb + cI] = v;
    } else {
      f32x2 hd, tl;
      hd.x = (kk == 0) ? 1.0f : 0.0f;
      hd.y = (kk == 1) ? 1.0f : 0.0f;
      tl.x = (kk == 1022) ? 1.0f : 0.0f;
      tl.y = (kk == 1023) ? 1.0f : 0.0f;
      *(f32x2*)&out_enc[rb] = hd;
      *(f32x2*)&out_enc[rb + 1022] = tl;
    }
  }

  // block loss reduce -> one atomic
  for (int off = 32; off; off >>= 1) ls += __shfl_down(ls, off);
  if (lane == 0) redf[w] = ls;
  __syncthreads();
  if (t == 0) atomicAdd(lsum, redf[0] + redf[1] + redf[2] + redf[3]);
}

// K_scalars: loss + perplexity
__global__ __launch_bounds__(1024) void k_scalars(const int* __restrict__ cnt,
                                                  const float* __restrict__ lsum,
                                                  float* __restrict__ out) {
  int t = threadIdx.x;
  float p = (float)cnt[t] * (1.0f / 65536.0f);
  float term = fmul_rn_(p, logf(fadd_rn_(p, 1e-10f)));
  for (int off = 32; off; off >>= 1) term += __shfl_down(term, off);
  __shared__ float red[16];
  if ((t & 63) == 0) red[t >> 6] = term;
  __syncthreads();
  if (t == 0) {
    float s = 0.f;
#pragma unroll
    for (int w = 0; w < 16; ++w) s += red[w];
    out[PPL_OFF] = expf(-s);
    float e = *lsum * (1.0f / 8388608.0f);
    out[0] = fadd_rn_(e, fmul_rn_(0.25f, e));  // q_latent + 0.25*e_latent (equal)
  }
}

extern "C" void kernel_launch(void* const* d_in, const int* in_sizes, int n_in,
                              void* d_out, int out_size, void* d_ws, size_t ws_size,
                              hipStream_t stream) {
  const float* inp = (const float*)d_in[0];
  const float* cb = (const float*)d_in[1];
  float* out = (float*)d_out;

  _Float16* Bp = (_Float16*)d_ws;          // 16*18432 halfs = 589824 B
  float* cbT = (float*)(Bp + 16 * CHUNKH); // 131072 f32
  float* cc = cbT + DIM * KC;              // 1024 f32
  int* cnt = (int*)(cc + KC);              // 1024 i32
  float* lsum = (float*)(cnt + KC);        // 1 f32

  (void)hipMemsetAsync(cnt, 0, (KC + 1) * sizeof(int), stream);
  k_prep<<<KC / 64, 256, 0, stream>>>(cb, cbT, cc, Bp);
  k_main<<<NROWS / 64, 256, 0, stream>>>(inp, cb, cbT, Bp, cc,
                                         out + QST_OFF, out + ENC_OFF, cnt, lsum);
  k_scalars<<<1, 1024, 0, stream>>>(cnt, lsum, out);
}

// Round 6
// 412.028 us; speedup vs baseline: 1.4318x; 1.3309x over previous
//
#include <hip/hip_runtime.h>

// VectorQuantizer: inputs [65536,128] f32, codebook [1024,128] f32.
// Outputs flat f32: loss(1) | quantized_st(65536*128) | perplexity(1) | encodings(65536*1024)
#define NROWS 65536
#define DIM   128
#define KC    1024
#define QST_OFF  1
#define PPL_OFF  8388609
#define ENC_OFF  8388610

typedef float f32x2 __attribute__((ext_vector_type(2)));
typedef float floatx4 __attribute__((ext_vector_type(4)));
typedef _Float16 half8_t __attribute__((ext_vector_type(8)));
typedef _Float16 half4_t __attribute__((ext_vector_type(4)));

// B/A LDS stride: 144 halfs (288 B)
#define BSTR 144
#define TILEH (64 * BSTR)          // 9216 halfs per split tile
#define CHUNKH (2 * TILEH)         // 18432 halfs per chunk (hi+lo)

// --- rounding-exact helpers: numpy-replica fp32 elementwise ops, no contraction ---
__device__ __forceinline__ float fadd_rn_(float a, float b) {
#pragma clang fp contract(off)
  return a + b;
}
__device__ __forceinline__ float fsub_rn_(float a, float b) {
#pragma clang fp contract(off)
  return a - b;
}
__device__ __forceinline__ float fmul_rn_(float a, float b) {
#pragma clang fp contract(off)
  return a * b;
}

// numpy pairwise_sum(x*x) for n=128: 8 accumulators, strided, fixed combine tree.
__device__ __forceinline__ float rowsq128(const float4* src) {
  float r[8];
  {
    float4 v0 = src[0], v1 = src[1];
    r[0] = fmul_rn_(v0.x, v0.x); r[1] = fmul_rn_(v0.y, v0.y);
    r[2] = fmul_rn_(v0.z, v0.z); r[3] = fmul_rn_(v0.w, v0.w);
    r[4] = fmul_rn_(v1.x, v1.x); r[5] = fmul_rn_(v1.y, v1.y);
    r[6] = fmul_rn_(v1.z, v1.z); r[7] = fmul_rn_(v1.w, v1.w);
  }
  for (int i = 1; i < 16; ++i) {
    float4 v0 = src[2 * i], v1 = src[2 * i + 1];
    r[0] = fadd_rn_(r[0], fmul_rn_(v0.x, v0.x));
    r[1] = fadd_rn_(r[1], fmul_rn_(v0.y, v0.y));
    r[2] = fadd_rn_(r[2], fmul_rn_(v0.z, v0.z));
    r[3] = fadd_rn_(r[3], fmul_rn_(v0.w, v0.w));
    r[4] = fadd_rn_(r[4], fmul_rn_(v1.x, v1.x));
    r[5] = fadd_rn_(r[5], fmul_rn_(v1.y, v1.y));
    r[6] = fadd_rn_(r[6], fmul_rn_(v1.z, v1.z));
    r[7] = fadd_rn_(r[7], fmul_rn_(v1.w, v1.w));
  }
  return fadd_rn_(fadd_rn_(fadd_rn_(r[0], r[1]), fadd_rn_(r[2], r[3])),
                  fadd_rn_(fadd_rn_(r[4], r[5]), fadd_rn_(r[6], r[7])));
}

// K_prep (16 blocks x 64 codes): cbT transpose, exact cc chain, fp16 hi/lo pack.
__global__ __launch_bounds__(256) void k_prep(const float* __restrict__ cb,
                                              float* __restrict__ cbT,
                                              float* __restrict__ cc,
                                              _Float16* __restrict__ Bp) {
  __shared__ float tile[64 * 129];  // +1 pad: conflict-free transpose
  int t = threadIdx.x;
  int c0 = blockIdx.x * 64;
#pragma unroll
  for (int it = 0; it < 32; ++it) {
    int f = it * 256 + t;
    int c = f >> 7, d = f & 127;
    tile[c * 129 + d] = cb[(size_t)(c0 + c) * DIM + d];
  }
  __syncthreads();
#pragma unroll
  for (int it = 0; it < 32; ++it) {
    int f = it * 256 + t;
    int d = f >> 6, c = f & 63;
    cbT[(size_t)d * KC + c0 + c] = tile[c * 129 + d];
  }
  if (t < 64) {
    const float* s = &tile[t * 129];
    float r[8];
#pragma unroll
    for (int j = 0; j < 8; ++j) r[j] = fmul_rn_(s[j], s[j]);
    for (int i = 1; i < 16; ++i) {
#pragma unroll
      for (int j = 0; j < 8; ++j)
        r[j] = fadd_rn_(r[j], fmul_rn_(s[i * 8 + j], s[i * 8 + j]));
    }
    cc[c0 + t] = fadd_rn_(fadd_rn_(fadd_rn_(r[0], r[1]), fadd_rn_(r[2], r[3])),
                          fadd_rn_(fadd_rn_(r[4], r[5]), fadd_rn_(r[6], r[7])));
  }
  size_t base = (size_t)blockIdx.x * CHUNKH;
#pragma unroll
  for (int it = 0; it < 32; ++it) {
    int f = it * 256 + t;
    int c = f >> 7, k = f & 127;
    float c5 = tile[c * 129 + k] * 512.0f;  // exact pow2 scale
    _Float16 h = (_Float16)c5;
    _Float16 l = (_Float16)(c5 - (float)h);
    Bp[base + c * BSTR + k] = h;
    Bp[base + TILEH + c * BSTR + k] = l;
  }
}

// K_main: 64 rows/block. fp16-split MFMA distance GEMM + margin argmin +
// inline exact recheck + fused epilogue. B staged per chunk with TRANSIENT
// registers only (nothing live across the MFMA section -> no spill).
__global__ __launch_bounds__(256, 4) void k_main(const float* __restrict__ inp,
                                                 const float* __restrict__ cb,
                                                 const float* __restrict__ cbT,
                                                 const _Float16* __restrict__ Bp,
                                                 const float* __restrict__ cc,
                                                 float* __restrict__ out_qst,
                                                 float* __restrict__ out_enc,
                                                 int* __restrict__ cnt,
                                                 float* __restrict__ lsum) {
  __shared__ _Float16 SB[CHUNKH];  // 36864 B: A-split image, then B chunk images
  __shared__ float xxs[64];
  __shared__ int bk[64];
  __shared__ int fl_rows[64];
  __shared__ int fl_cnt;
  __shared__ float xs[128];
  __shared__ float redd[4];
  __shared__ int redi[4];
  __shared__ float redf[4];

  int t = threadIdx.x;
  int lane = t & 63, w = t >> 6;
  int q = lane >> 4, col = lane & 15;
  int row0 = blockIdx.x * 64;
  if (t == 0) fl_cnt = 0;

  // ---- stage A as fp16 hi/lo split (all threads, coalesced) ----
  {
    int r = t & 63, seg = t >> 6;
    const float* src = inp + (size_t)(row0 + r) * DIM + seg * 32;
#pragma unroll
    for (int i = 0; i < 8; ++i) {
      float4 v = *(const float4*)(src + i * 4);
      _Float16 h0 = (_Float16)v.x, h1 = (_Float16)v.y, h2 = (_Float16)v.z, h3 = (_Float16)v.w;
      half4_t hv = {h0, h1, h2, h3};
      half4_t lv = {(_Float16)(v.x - (float)h0), (_Float16)(v.y - (float)h1),
                    (_Float16)(v.z - (float)h2), (_Float16)(v.w - (float)h3)};
      int k = seg * 32 + i * 4;
      *(half4_t*)&SB[r * BSTR + k] = hv;
      *(half4_t*)&SB[TILEH + r * BSTR + k] = lv;
    }
  }
  // exact xx chain, one lane per row (row just fetched -> cache-hot)
  if (t < 64) xxs[t] = rowsq128((const float4*)(inp + (size_t)(row0 + t) * DIM));
  __syncthreads();

  // ---- A frags -> registers ----
  int arow = w * 16 + col;
  half8_t ah[4], al[4];
#pragma unroll
  for (int ks = 0; ks < 4; ++ks) {
    ah[ks] = *(const half8_t*)&SB[arow * BSTR + ks * 32 + q * 8];
    al[ks] = *(const half8_t*)&SB[TILEH + arow * BSTR + ks * 32 + q * 8];
  }
  float xr[4];
#pragma unroll
  for (int r = 0; r < 4; ++r) xr[r] = xxs[w * 16 + q * 4 + r];

  float b1[4], b2[4];
  int i1[4];
#pragma unroll
  for (int r = 0; r < 4; ++r) { b1[r] = 3.4e38f; b2[r] = 3.4e38f; i1[r] = 0; }

  const float4* bp4 = (const float4*)Bp;  // chunk stride = 2304 float4

  for (int c = 0; c < 16; ++c) {
    __syncthreads();  // prior chunk LDS reads (and A-frag reads, iter 0) complete
    {
      // transient-register staging: load 9x float4 then store; no liveness
      // across the MFMA section below (anti-spill — R5 post-mortem)
      float4 br[9];
#pragma unroll
      for (int r = 0; r < 9; ++r) br[r] = bp4[c * 2304 + r * 256 + t];
#pragma unroll
      for (int r = 0; r < 9; ++r) *(float4*)&SB[(size_t)(r * 256 + t) * 8] = br[r];
    }
    __syncthreads();

    float cck[4];
#pragma unroll
    for (int ct = 0; ct < 4; ++ct) cck[ct] = cc[c * 64 + ct * 16 + col];

    floatx4 acc[4];
#pragma unroll
    for (int ct = 0; ct < 4; ++ct) acc[ct] = (floatx4){0.f, 0.f, 0.f, 0.f};

#pragma unroll
    for (int ks = 0; ks < 4; ++ks) {
#pragma unroll
      for (int ct = 0; ct < 4; ++ct) {
        int brow = ct * 16 + col;
        half8_t bh = *(const half8_t*)&SB[brow * BSTR + ks * 32 + q * 8];
        half8_t bl = *(const half8_t*)&SB[TILEH + brow * BSTR + ks * 32 + q * 8];
        acc[ct] = __builtin_amdgcn_mfma_f32_16x16x32_f16(ah[ks], bh, acc[ct], 0, 0, 0);
        acc[ct] = __builtin_amdgcn_mfma_f32_16x16x32_f16(ah[ks], bl, acc[ct], 0, 0, 0);
        acc[ct] = __builtin_amdgcn_mfma_f32_16x16x32_f16(al[ks], bh, acc[ct], 0, 0, 0);
      }
    }

#pragma unroll
    for (int ct = 0; ct < 4; ++ct) {
#pragma unroll
      for (int r = 0; r < 4; ++r) {
        float m2 = fmul_rn_(acc[ct][r], 0.00390625f);  // fl(2*matmul), exact unscale
        float dist = fsub_rn_(fadd_rn_(xr[r], cck[ct]), m2);
        int kidx = c * 64 + ct * 16 + col;
        bool lt = dist < b1[r];
        b2[r] = lt ? b1[r] : fminf(b2[r], dist);
        i1[r] = lt ? kidx : i1[r];
        b1[r] = lt ? dist : b1[r];
      }
    }
  }

  // top-2 reduce across the 16 col-lanes; tie -> lower index
#pragma unroll
  for (int r = 0; r < 4; ++r) {
    float v1 = b1[r], v2 = b2[r];
    int ii = i1[r];
    for (int off = 1; off < 16; off <<= 1) {
      float ov1 = __shfl_xor(v1, off);
      float ov2 = __shfl_xor(v2, off);
      int oi = __shfl_xor(ii, off);
      float nb1 = fminf(v1, ov1);
      float nb2 = fminf(fmaxf(v1, ov1), fminf(v2, ov2));
      ii = (ov1 < v1) ? oi : ((ov1 > v1) ? ii : min(ii, oi));
      v1 = nb1; v2 = nb2;
    }
    b1[r] = v1; b2[r] = v2; i1[r] = ii;
  }

  if (col == 0) {
#pragma unroll
    for (int r = 0; r < 4; ++r) {
      int lrow = w * 16 + q * 4 + r;
      bk[lrow] = i1[r];
      float u = (b1[r] >= 256.f) ? 9.4e-5f : 4.7e-5f;  // 3-ulp tiered margin
      if (b2[r] - b1[r] < u) {
        int p = atomicAdd(&fl_cnt, 1);
        fl_rows[p] = lrow;
      }
    }
  }
  __syncthreads();

  // ---- inline exact fp32 recheck of flagged rows (cbT column scan; rare) ----
  int nf = fl_cnt;
  for (int f = 0; f < nf; ++f) {
    int row = fl_rows[f];
    if (t < 128) xs[t] = inp[(size_t)(row0 + row) * DIM + t];
    __syncthreads();
    float xxr = xxs[row];
    int c0 = t * 4;
    float a0 = 0.f, a1 = 0.f, a2 = 0.f, a3 = 0.f;
    for (int d = 0; d < 128; ++d) {
      float xd = xs[d];
      float4 cv = *(const float4*)&cbT[(size_t)d * KC + c0];
      a0 = __builtin_fmaf(xd, cv.x, a0);
      a1 = __builtin_fmaf(xd, cv.y, a1);
      a2 = __builtin_fmaf(xd, cv.z, a2);
      a3 = __builtin_fmaf(xd, cv.w, a3);
    }
    float aa[4] = {a0, a1, a2, a3};
    float bb = 3.4e38f;
    int bi = 0;
#pragma unroll
    for (int j = 0; j < 4; ++j) {
      float dist = fsub_rn_(fadd_rn_(xxr, cc[c0 + j]), fmul_rn_(2.0f, aa[j]));
      if (dist < bb) { bb = dist; bi = c0 + j; }
    }
    for (int off = 1; off < 64; off <<= 1) {
      float ov = __shfl_xor(bb, off);
      int oi = __shfl_xor(bi, off);
      if (ov < bb || (ov == bb && oi < bi)) { bb = ov; bi = oi; }
    }
    if (lane == 0) { redd[w] = bb; redi[w] = bi; }
    __syncthreads();
    if (t == 0) {
      float vb = redd[0];
      int ib = redi[0];
#pragma unroll
      for (int ww = 1; ww < 4; ++ww) {
        if (redd[ww] < vb || (redd[ww] == vb && redi[ww] < ib)) { vb = redd[ww]; ib = redi[ww]; }
      }
      bk[row] = ib;
    }
    __syncthreads();
  }

  // ---- epilogue (R1-proven write patterns: 297 MB measured) ----
  if (t < 64) atomicAdd(&cnt[bk[t]], 1);

  float ls = 0.f;
#pragma unroll 4
  for (int it = 0; it < 32; ++it) {
    int f = it * 256 + t;  // 64 rows x 128 d, linear
    int row = f >> 7, d = f & 127;
    size_t gro = (size_t)(row0 + row) * DIM + d;
    float x = inp[gro];
    float qv = cb[(size_t)bk[row] * DIM + d];
    float qe = fsub_rn_(qv, x);
    out_qst[gro] = fadd_rn_(x, qe);  // == np: inputs + (quantized - inputs)
    ls = __builtin_fmaf(qe, qe, ls);
  }

  // encodings: linear f32x2 walk across the block's 256 KB (R1-proven)
  for (int it = 0; it < 128; ++it) {
    int f2 = it * 256 + t;  // 64 rows x 512 f32x2
    int row = f2 >> 9, c2 = f2 & 511;
    int kk = bk[row];
    f32x2 v;
    v.x = (kk == 2 * c2) ? 1.0f : 0.0f;
    v.y = (kk == 2 * c2 + 1) ? 1.0f : 0.0f;
    *(f32x2*)&out_enc[(size_t)(row0 + row) * KC + 2 * c2] = v;
  }

  // block loss reduce -> one atomic
  for (int off = 32; off; off >>= 1) ls += __shfl_down(ls, off);
  if (lane == 0) redf[w] = ls;
  __syncthreads();
  if (t == 0) atomicAdd(lsum, redf[0] + redf[1] + redf[2] + redf[3]);
}

// K_scalars: loss + perplexity
__global__ __launch_bounds__(1024) void k_scalars(const int* __restrict__ cnt,
                                                  const float* __restrict__ lsum,
                                                  float* __restrict__ out) {
  int t = threadIdx.x;
  float p = (float)cnt[t] * (1.0f / 65536.0f);
  float term = fmul_rn_(p, logf(fadd_rn_(p, 1e-10f)));
  for (int off = 32; off; off >>= 1) term += __shfl_down(term, off);
  __shared__ float red[16];
  if ((t & 63) == 0) red[t >> 6] = term;
  __syncthreads();
  if (t == 0) {
    float s = 0.f;
#pragma unroll
    for (int w = 0; w < 16; ++w) s += red[w];
    out[PPL_OFF] = expf(-s);
    float e = *lsum * (1.0f / 8388608.0f);
    out[0] = fadd_rn_(e, fmul_rn_(0.25f, e));  // q_latent + 0.25*e_latent (equal)
  }
}

extern "C" void kernel_launch(void* const* d_in, const int* in_sizes, int n_in,
                              void* d_out, int out_size, void* d_ws, size_t ws_size,
                              hipStream_t stream) {
  const float* inp = (const float*)d_in[0];
  const float* cb = (const float*)d_in[1];
  float* out = (float*)d_out;

  _Float16* Bp = (_Float16*)d_ws;          // 16*18432 halfs = 589824 B
  float* cbT = (float*)(Bp + 16 * CHUNKH); // 131072 f32
  float* cc = cbT + DIM * KC;              // 1024 f32
  int* cnt = (int*)(cc + KC);              // 1024 i32
  float* lsum = (float*)(cnt + KC);        // 1 f32

  (void)hipMemsetAsync(cnt, 0, (KC + 1) * sizeof(int), stream);
  k_prep<<<KC / 64, 256, 0, stream>>>(cb, cbT, cc, Bp);
  k_main<<<NROWS / 64, 256, 0, stream>>>(inp, cb, cbT, Bp, cc,
                                         out + QST_OFF, out + ENC_OFF, cnt, lsum);
  k_scalars<<<1, 1024, 0, stream>>>(cnt, lsum, out);
}